// Round 10
// baseline (292.509 us; speedup 1.0000x reference)
//
#include <hip/hip_runtime.h>
#include <hip/hip_bf16.h>
#include <stdint.h>

typedef __attribute__((ext_vector_type(8)))  short    s16x8;
typedef __attribute__((ext_vector_type(16))) float    f32x16;
typedef __attribute__((ext_vector_type(4)))  float    f32x4;
typedef __attribute__((ext_vector_type(4)))  unsigned u32x4;

#define KSUB 8
#define SUBSZ  27648
#define OFF_W  0
#define OFF_W1 24576
#define OFF_W5 26624
#define OFF_B  26752

// ws layout: [0, SUBSZ*8) weights; counts (8 x 64B); te[9]; buckets
#define WS_CNT (SUBSZ * KSUB)
#define WS_TE  (WS_CNT + 512)
#define WS_BKT (WS_CNT + 1024)

#define LOG2E 1.4426950408889634f
#define TWOLOG2E 2.885390081777927f
#define TAU 1e-3f    // skip threshold; skip error <= ~8*TAU*|o|max ~ 0.02

__device__ __forceinline__ float fast_tanh(float z) {
  float e = __builtin_amdgcn_exp2f(z * TWOLOG2E);
  return __builtin_fmaf(-2.0f, __builtin_amdgcn_rcpf(e + 1.0f), 1.0f);
}
__device__ __forceinline__ float tanh_pre(float zeta) {
  float e = __builtin_amdgcn_exp2f(zeta);
  return __builtin_fmaf(-2.0f, __builtin_amdgcn_rcpf(e + 1.0f), 1.0f);
}
__device__ __forceinline__ unsigned packbf(float lo, float hi) {
  unsigned ul = __builtin_bit_cast(unsigned, lo) + 0x8000u;
  unsigned uh = __builtin_bit_cast(unsigned, hi) + 0x8000u;
  return __builtin_amdgcn_perm(uh, ul, 0x07060302u);
}
__device__ __forceinline__ f32x16 mfma_bf16(s16x8 a, s16x8 b, f32x16 c) {
  return __builtin_amdgcn_mfma_f32_32x32x16_bf16(a, b, c, 0, 0, 0);
}

// C layout (32x32): col = lane&31 (=point), row j = (r&3)+8*(r>>2)+4*(lane>>5).
__device__ __forceinline__ void epilogue(const f32x16& acc0, const f32x16& acc1,
                                         unsigned Bu[16]) {
#pragma unroll
  for (int kt = 0; kt < 4; ++kt) {
#pragma unroll
    for (int qq = 0; qq < 2; ++qq) {
      const int ra = ((2 * kt) & 3) * 4 + 2 * qq;
      const int rb = ((2 * kt + 1) & 3) * 4 + 2 * qq;
      float a0v, a1v, b0v, b1v;
      if (kt < 2) { a0v = acc0[ra]; a1v = acc0[ra + 1]; b0v = acc0[rb]; b1v = acc0[rb + 1]; }
      else        { a0v = acc1[ra]; a1v = acc1[ra + 1]; b0v = acc1[rb]; b1v = acc1[rb + 1]; }
      unsigned P0 = packbf(tanh_pre(a0v), tanh_pre(a1v));
      unsigned P1 = packbf(tanh_pre(b0v), tanh_pre(b1v));
      auto pr = __builtin_amdgcn_permlane32_swap(P0, P1, false, false);
      Bu[kt * 4 + qq]     = pr[0];
      Bu[kt * 4 + qq + 2] = pr[1];
    }
  }
}

__global__ void prep_weights(const float* __restrict__ W1, const float* __restrict__ b1,
                             const float* __restrict__ W2, const float* __restrict__ b2,
                             const float* __restrict__ W3, const float* __restrict__ b3,
                             const float* __restrict__ W4, const float* __restrict__ b4,
                             const float* __restrict__ W5, const float* __restrict__ scales,
                             char* __restrict__ ws) {
  const int sub = blockIdx.x;
  const int tid = threadIdx.x;
  if (sub == 0 && tid < 128) ((unsigned*)(ws + WS_CNT))[tid] = 0;   // zero counts(+te)
  char* dst = ws + sub * SUBSZ;
  const float s0 = TWOLOG2E * scales[sub * 4 + 0];
  const float s1 = TWOLOG2E * scales[sub * 4 + 1];
  const float s2 = TWOLOG2E * scales[sub * 4 + 2];
  const float s3 = TWOLOG2E * scales[sub * 4 + 3];
#pragma unroll
  for (int l = 0; l < 3; ++l) {
    const float* src = (l == 0) ? (W2 + sub * 4096) : (l == 1) ? (W3 + sub * 4096) : (W4 + sub * 4096);
    const float sc   = (l == 0) ? s1 : (l == 1) ? s2 : s3;
    __hip_bfloat16* d = (__hip_bfloat16*)(dst + OFF_W + l * 8192);
    for (int idx = tid; idx < 4096; idx += 256) {
      int row = idx >> 6, col = idx & 63;
      int de = row * 64 + (col ^ ((row & 7) << 3));   // XOR swizzle (16B granules)
      d[de] = __float2bfloat16(sc * src[idx]);
    }
  }
  {
    __hip_bfloat16* d = (__hip_bfloat16*)(dst + OFF_W1);
    for (int idx = tid; idx < 1024; idx += 256) {
      int row = idx >> 4, kc = idx & 15;
      float v = 0.f;
      if (kc < 3)       v = s0 * W1[sub * 192 + row * 3 + kc];
      else if (kc == 3) v = s0 * b1[sub * 64 + row];
      d[idx] = __float2bfloat16(v);
    }
  }
  if (tid < 64) {
    ((__hip_bfloat16*)(dst + OFF_W5))[tid] = __float2bfloat16(W5[sub * 64 + tid]);
    ((float*)(dst + OFF_B))[tid]        = s1 * b2[sub * 64 + tid];
    ((float*)(dst + OFF_B + 256))[tid]  = s2 * b3[sub * 64 + tid];
    ((float*)(dst + OFF_B + 512))[tid]  = s3 * b4[sub * 64 + tid];
  }
}

// ---------- stage A: gating + bucket fill (2-pass), also zeroes out[] ----------
#define GCHUNK 8
__global__ __launch_bounds__(256) void gate_bucket(
    const float* __restrict__ X, const float* __restrict__ T,
    const float* __restrict__ centers, const float* __restrict__ lgam,
    unsigned* __restrict__ counts, unsigned* __restrict__ buckets,
    float* __restrict__ out, int n) {
  __shared__ unsigned tot[8], cursor[8];
  const int tid  = threadIdx.x;
  const int lane = tid & 63;
  const int base = blockIdx.x * (256 * GCHUNK);
  if (tid < 8) tot[tid] = 0;
  __syncthreads();

  for (int c = 0; c < GCHUNK; ++c) {
    const int p = base + c * 256 + tid;
    const float x = X[p], tt = T[p];
    out[p] = 0.f;                                      // fused memset
    float lgv[8]; float m = -1e30f;
#pragma unroll
    for (int i = 0; i < 8; ++i) {
      float gx = __builtin_amdgcn_exp2f(lgam[2 * i] * LOG2E);
      float gt = __builtin_amdgcn_exp2f(lgam[2 * i + 1] * LOG2E);
      float dx = x - centers[2 * i], dt = tt - centers[2 * i + 1];
      float lg = -(gx * dx * dx + gt * dt * dt);
      lgv[i] = lg; m = fmaxf(m, lg);
    }
    float S = 0.f; float ev[8];
#pragma unroll
    for (int i = 0; i < 8; ++i) { ev[i] = __builtin_amdgcn_exp2f((lgv[i] - m) * LOG2E); S += ev[i]; }
    const float thr = TAU * S;
#pragma unroll
    for (int i = 0; i < 8; ++i) {
      unsigned long long b = __ballot(ev[i] > thr);
      if (lane == 0) atomicAdd(&tot[i], (unsigned)__popcll(b));
    }
  }
  __syncthreads();
  if (tid < 8) cursor[tid] = atomicAdd(&counts[tid * 16], tot[tid]);
  __syncthreads();

  for (int c = 0; c < GCHUNK; ++c) {
    const int p = base + c * 256 + tid;
    const float x = X[p], tt = T[p];
    float lgv[8]; float m = -1e30f;
#pragma unroll
    for (int i = 0; i < 8; ++i) {
      float gx = __builtin_amdgcn_exp2f(lgam[2 * i] * LOG2E);
      float gt = __builtin_amdgcn_exp2f(lgam[2 * i + 1] * LOG2E);
      float dx = x - centers[2 * i], dt = tt - centers[2 * i + 1];
      float lg = -(gx * dx * dx + gt * dt * dt);
      lgv[i] = lg; m = fmaxf(m, lg);
    }
    float S = 0.f; float ev[8];
#pragma unroll
    for (int i = 0; i < 8; ++i) { ev[i] = __builtin_amdgcn_exp2f((lgv[i] - m) * LOG2E); S += ev[i]; }
    const float thr = TAU * S;
    const float rS = __builtin_amdgcn_rcpf(S);
#pragma unroll
    for (int i = 0; i < 8; ++i) {
      unsigned long long b = __ballot(ev[i] > thr);
      unsigned cw = (unsigned)__popcll(b);
      unsigned wb = 0;
      if (lane == 0 && cw) wb = atomicAdd(&cursor[i], cw);
      wb = __shfl(wb, 0);
      if (ev[i] > thr) {
        unsigned pre = __builtin_amdgcn_mbcnt_hi((unsigned)(b >> 32),
                        __builtin_amdgcn_mbcnt_lo((unsigned)b, 0u));
        unsigned wq = (unsigned)(ev[i] * rS * 4095.f + 0.5f);   // 12-bit weight
        buckets[(size_t)i * n + wb + pre] = (wq << 20) | (unsigned)p;
      }
    }
  }
}

// ---------- tile prefix: te[i] = cumulative ceil(cnt/128) ----------
__global__ void make_tiles(const unsigned* __restrict__ counts, unsigned* __restrict__ te) {
  if (threadIdx.x == 0) {
    unsigned acc = 0;
#pragma unroll
    for (int i = 0; i < 8; ++i) { te[i] = acc; acc += (counts[i * 16] + 127u) >> 7; }
    te[8] = acc;
  }
}

// ---------- stage B: persistent eval over compacted tiles ----------
#define EVG 2048
__global__ __launch_bounds__(256) void pinn_eval(
    const float* __restrict__ X, const float* __restrict__ T,
    const char* __restrict__ ws, const float* __restrict__ b5,
    const unsigned* __restrict__ counts, const unsigned* __restrict__ buckets,
    const unsigned* __restrict__ te, float* __restrict__ out, int n) {
  __shared__ __align__(16) char smem[SUBSZ];
  __shared__ unsigned ste[9];
  const int tid  = threadIdx.x;
  const int lane = tid & 63;
  const int wid  = tid >> 6;
  const int g    = lane >> 5;
  const int lpt  = lane & 31;

  if (tid < 9) ste[tid] = te[tid];
  __syncthreads();
  const unsigned total = ste[8];
  const unsigned tpb = (total + EVG - 1) / EVG;
  const unsigned t0 = blockIdx.x * tpb;
  const unsigned t1 = (t0 + tpb < total) ? (t0 + tpb) : total;
  if (t0 >= total) return;

  int cur_sub = -1;
  for (unsigned tile = t0; tile < t1; ++tile) {
    int sub = 0;
    while (ste[sub + 1] <= tile) ++sub;            // uniform, <=8 iters
    const unsigned cnt   = counts[sub * 16];
    const unsigned ltile = tile - ste[sub];

    if (sub != cur_sub) {
      __syncthreads();                              // prior tile done reading smem
      const char* gb = ws + sub * SUBSZ;
      for (int ch = wid; ch < SUBSZ / 1024; ch += 4) {
        *(f32x4*)(smem + ch * 1024 + lane * 16) = *(const f32x4*)(gb + ch * 1024 + lane * 16);
      }
      cur_sub = sub;
      __syncthreads();
    }

    const unsigned j = ltile * 128u + wid * 32u + (unsigned)lpt;
    const bool valid = j < cnt;
    const unsigned jj = valid ? j : (cnt - 1);
    const unsigned ent = buckets[(size_t)sub * n + jj];
    const unsigned pidx = ent & 0xFFFFFu;
    const float wsub = (float)(ent >> 20) * (1.0f / 4095.0f);
    const float x  = X[pidx];
    const float tt = T[pidx];

    float rr = x * 0.5f;
    rr = rr - floorf(rr);
    const float cpx = __builtin_amdgcn_cosf(rr);
    const float spx = __builtin_amdgcn_sinf(rr);
    unsigned b00 = packbf(cpx, spx);
    unsigned b01 = packbf(tt, 1.0f);
    if (g) { b00 = 0u; b01 = 0u; }

    f32x16 acc0, acc1;
#pragma unroll
    for (int r = 0; r < 16; ++r) { acc0[r] = 0.f; acc1[r] = 0.f; }
    s16x8 a0 = *(const s16x8*)(smem + OFF_W1 + lpt * 32 + g * 16);
    s16x8 a1 = *(const s16x8*)(smem + OFF_W1 + (32 + lpt) * 32 + g * 16);
    u32x4 blv; blv[0] = b00; blv[1] = b01; blv[2] = 0u; blv[3] = 0u;
    s16x8 bl1 = __builtin_bit_cast(s16x8, blv);
    acc0 = mfma_bf16(a0, bl1, acc0);
    acc1 = mfma_bf16(a1, bl1, acc1);
    unsigned Bu[16];
    epilogue(acc0, acc1, Bu);

    for (int l = 0; l < 3; ++l) {
      const float* bias = (const float*)(smem + OFF_B + l * 256);
#pragma unroll
      for (int rq = 0; rq < 4; ++rq) {
        f32x4 bv0 = *(const f32x4*)(bias + 8 * rq + 4 * g);
        f32x4 bv1 = *(const f32x4*)(bias + 32 + 8 * rq + 4 * g);
#pragma unroll
        for (int rr2 = 0; rr2 < 4; ++rr2) { acc0[4 * rq + rr2] = bv0[rr2]; acc1[4 * rq + rr2] = bv1[rr2]; }
      }
      const char* wbase = smem + OFF_W + l * 8192;
#pragma unroll
      for (int kt = 0; kt < 4; ++kt) {
        const int coff = ((16 * kt + 8 * g) * 2) ^ ((lpt & 7) << 4);
        s16x8 wa0 = *(const s16x8*)(wbase + lpt * 128 + coff);
        s16x8 wa1 = *(const s16x8*)(wbase + (32 + lpt) * 128 + coff);
        u32x4 bb; bb[0] = Bu[kt * 4]; bb[1] = Bu[kt * 4 + 1]; bb[2] = Bu[kt * 4 + 2]; bb[3] = Bu[kt * 4 + 3];
        s16x8 bf = __builtin_bit_cast(s16x8, bb);
        acc0 = mfma_bf16(wa0, bf, acc0);
        acc1 = mfma_bf16(wa1, bf, acc1);
      }
      epilogue(acc0, acc1, Bu);
    }

    const float b5s = b5[sub];
    f32x16 acc5;
#pragma unroll
    for (int r = 0; r < 16; ++r) acc5[r] = b5s;
#pragma unroll
    for (int kt = 0; kt < 4; ++kt) {
      s16x8 w5f = *(const s16x8*)(smem + OFF_W5 + (kt * 16 + 8 * g) * 2);
      u32x4 bb; bb[0] = Bu[kt * 4]; bb[1] = Bu[kt * 4 + 1]; bb[2] = Bu[kt * 4 + 2]; bb[3] = Bu[kt * 4 + 3];
      s16x8 bf = __builtin_bit_cast(s16x8, bb);
      acc5 = mfma_bf16(w5f, bf, acc5);
    }

    if ((lane < 32) && valid) atomicAdd(&out[pidx], wsub * acc5[0]);
  }
}

// ---------- stage C: finalize ----------
__global__ __launch_bounds__(256) void finalize(
    const float* __restrict__ X, const float* __restrict__ T,
    float* __restrict__ out) {
  const int p = blockIdx.x * 256 + threadIdx.x;
  const float x  = X[p];
  const float tt = T[p];
  float rr = x * 0.5f;
  rr = rr - floorf(rr);
  const float cpx = __builtin_amdgcn_cosf(rr);
  const float u0  = x * x * cpx;
  out[p] = fast_tanh(tt) * out[p] + u0;
}

// ---------- dense fallback (measured R6 path) ----------
__global__ __launch_bounds__(256) void pinn_main(
    const float* __restrict__ X, const float* __restrict__ T,
    const char* __restrict__ ws, const float* __restrict__ centers,
    const float* __restrict__ lgam, const float* __restrict__ b5,
    float* __restrict__ out) {
  __shared__ __align__(16) char smem[SUBSZ];
  const int tid  = threadIdx.x;
  const int lane = tid & 63;
  const int wid  = tid >> 6;
  const int g    = lane >> 5;
  const int lpt  = lane & 31;
  const int p    = blockIdx.x * 128 + wid * 32 + lpt;

  const float x  = X[p];
  const float tt = T[p];
  float rr = x * 0.5f;
  rr = rr - floorf(rr);
  const float cpx = __builtin_amdgcn_cosf(rr);
  const float spx = __builtin_amdgcn_sinf(rr);
  const float u0  = x * x * cpx;
  const float thT = fast_tanh(tt);

  float m = -1e30f;
#pragma unroll
  for (int i = 0; i < 8; ++i) {
    float gx = __builtin_amdgcn_exp2f(lgam[2 * i] * LOG2E);
    float gt = __builtin_amdgcn_exp2f(lgam[2 * i + 1] * LOG2E);
    float dx = x - centers[2 * i], dt = tt - centers[2 * i + 1];
    float lg = -(gx * dx * dx + gt * dt * dt);
    m = fmaxf(m, lg);
  }

  unsigned b00 = packbf(cpx, spx);
  unsigned b01 = packbf(tt, 1.0f);
  if (g) { b00 = 0u; b01 = 0u; }

  float uacc = 0.f, S = 0.f;

  for (int sub = 0; sub < KSUB; ++sub) {
    __syncthreads();
    const char* gb = ws + sub * SUBSZ;
    for (int ch = wid; ch < SUBSZ / 1024; ch += 4) {
      *(f32x4*)(smem + ch * 1024 + lane * 16) = *(const f32x4*)(gb + ch * 1024 + lane * 16);
    }
    __syncthreads();

    float gx = __builtin_amdgcn_exp2f(lgam[2 * sub] * LOG2E);
    float gt = __builtin_amdgcn_exp2f(lgam[2 * sub + 1] * LOG2E);
    float dx = x - centers[2 * sub], dtt = tt - centers[2 * sub + 1];
    float lg = -(gx * dx * dx + gt * dtt * dtt);
    float ei = __builtin_amdgcn_exp2f((lg - m) * LOG2E);

    f32x16 acc0, acc1;
#pragma unroll
    for (int r = 0; r < 16; ++r) { acc0[r] = 0.f; acc1[r] = 0.f; }
    s16x8 a0 = *(const s16x8*)(smem + OFF_W1 + lpt * 32 + g * 16);
    s16x8 a1 = *(const s16x8*)(smem + OFF_W1 + (32 + lpt) * 32 + g * 16);
    u32x4 blv; blv[0] = b00; blv[1] = b01; blv[2] = 0u; blv[3] = 0u;
    s16x8 bl1 = __builtin_bit_cast(s16x8, blv);
    acc0 = mfma_bf16(a0, bl1, acc0);
    acc1 = mfma_bf16(a1, bl1, acc1);
    unsigned Bu[16];
    epilogue(acc0, acc1, Bu);

    for (int l = 0; l < 3; ++l) {
      const float* bias = (const float*)(smem + OFF_B + l * 256);
#pragma unroll
      for (int rq = 0; rq < 4; ++rq) {
        f32x4 bv0 = *(const f32x4*)(bias + 8 * rq + 4 * g);
        f32x4 bv1 = *(const f32x4*)(bias + 32 + 8 * rq + 4 * g);
#pragma unroll
        for (int rr2 = 0; rr2 < 4; ++rr2) { acc0[4 * rq + rr2] = bv0[rr2]; acc1[4 * rq + rr2] = bv1[rr2]; }
      }
      const char* wbase = smem + OFF_W + l * 8192;
#pragma unroll
      for (int kt = 0; kt < 4; ++kt) {
        const int coff = ((16 * kt + 8 * g) * 2) ^ ((lpt & 7) << 4);
        s16x8 wa0 = *(const s16x8*)(wbase + lpt * 128 + coff);
        s16x8 wa1 = *(const s16x8*)(wbase + (32 + lpt) * 128 + coff);
        u32x4 bb; bb[0] = Bu[kt * 4]; bb[1] = Bu[kt * 4 + 1]; bb[2] = Bu[kt * 4 + 2]; bb[3] = Bu[kt * 4 + 3];
        s16x8 bf = __builtin_bit_cast(s16x8, bb);
        acc0 = mfma_bf16(wa0, bf, acc0);
        acc1 = mfma_bf16(wa1, bf, acc1);
      }
      epilogue(acc0, acc1, Bu);
    }

    const float b5s = b5[sub];
    f32x16 acc5;
#pragma unroll
    for (int r = 0; r < 16; ++r) acc5[r] = b5s;
#pragma unroll
    for (int kt = 0; kt < 4; ++kt) {
      s16x8 w5f = *(const s16x8*)(smem + OFF_W5 + (kt * 16 + 8 * g) * 2);
      u32x4 bb; bb[0] = Bu[kt * 4]; bb[1] = Bu[kt * 4 + 1]; bb[2] = Bu[kt * 4 + 2]; bb[3] = Bu[kt * 4 + 3];
      s16x8 bf = __builtin_bit_cast(s16x8, bb);
      acc5 = mfma_bf16(w5f, bf, acc5);
    }
    uacc = __builtin_fmaf(ei, acc5[0], uacc);
    S += ei;
  }

  float u = uacc * __builtin_amdgcn_rcpf(S);
  if (lane < 32) out[p] = thT * u + u0;
}

extern "C" void kernel_launch(void* const* d_in, const int* in_sizes, int n_in,
                              void* d_out, int out_size, void* d_ws, size_t ws_size,
                              hipStream_t stream) {
  const float* X   = (const float*)d_in[0];
  const float* T   = (const float*)d_in[1];
  const float* W1  = (const float*)d_in[2];
  const float* b1  = (const float*)d_in[3];
  const float* W2  = (const float*)d_in[4];
  const float* b2  = (const float*)d_in[5];
  const float* W3  = (const float*)d_in[6];
  const float* b3  = (const float*)d_in[7];
  const float* W4  = (const float*)d_in[8];
  const float* b4  = (const float*)d_in[9];
  const float* W5  = (const float*)d_in[10];
  const float* b5  = (const float*)d_in[11];
  const float* sc  = (const float*)d_in[12];
  const float* cen = (const float*)d_in[13];
  const float* lg  = (const float*)d_in[14];
  float* out = (float*)d_out;
  char*  ws  = (char*)d_ws;
  const int n = in_sizes[0];

  prep_weights<<<KSUB, 256, 0, stream>>>(W1, b1, W2, b2, W3, b3, W4, b4, W5, sc, ws);

  const size_t need = (size_t)WS_BKT + (size_t)KSUB * (size_t)n * 4ull;
  if (ws_size >= need) {
    unsigned* counts  = (unsigned*)(ws + WS_CNT);
    unsigned* te      = (unsigned*)(ws + WS_TE);
    unsigned* buckets = (unsigned*)(ws + WS_BKT);
    gate_bucket<<<n / (256 * GCHUNK), 256, 0, stream>>>(X, T, cen, lg, counts, buckets, out, n);
    make_tiles<<<1, 64, 0, stream>>>(counts, te);
    pinn_eval<<<EVG, 256, 0, stream>>>(X, T, ws, b5, counts, buckets, te, out, n);
    finalize<<<n / 256, 256, 0, stream>>>(X, T, out);
  } else {
    pinn_main<<<n / 128, 256, 0, stream>>>(X, T, ws, cen, lg, b5, out);
  }
}